// Round 1
// baseline (226.664 us; speedup 1.0000x reference)
//
#include <hip/hip_runtime.h>
#include <cstddef>

namespace {
constexpr int B = 4, C = 64, H = 256, W = 256;
constexpr int HW = H * W;      // 65536
constexpr int CHW = C * HW;    // 4194304
constexpr float SMIN = 0.6f, SMAX = 1.2f;
}

__global__ void init_mm_kernel(unsigned int* mm) {
  int i = threadIdx.x;
  if (i < B) { mm[i] = 0x7f7fffffu; mm[B + i] = 0u; }
}

// One block per (b, h) row. LDS-stage 3 rows (zero-padded halo), loop channels,
// accumulate mean Sobel energy; then block min/max reduce -> per-batch atomics.
__global__ __launch_bounds__(256) void edge_kernel(
    const float* __restrict__ x, float* __restrict__ edge,
    unsigned int* __restrict__ mm) {
  __shared__ float r0[258], r1[258], r2[258];
  __shared__ float smn[4], smx[4];
  const int bh = blockIdx.x;
  const int b = bh >> 8, h = bh & (H - 1);
  const int w = threadIdx.x;
  if (w < 2) { int e = w * 257; r0[e] = 0.f; r1[e] = 0.f; r2[e] = 0.f; }
  const float* xb = x + (size_t)b * CHW + (size_t)h * W + w;
  const bool hm = (h > 0), hp = (h < H - 1);
  float acc = 0.f;
  for (int c = 0; c < C; ++c) {
    const float* p = xb + (size_t)c * HW;
    __syncthreads();  // previous iteration's LDS reads done (also covers halo init)
    r0[w + 1] = hm ? p[-W] : 0.f;
    r1[w + 1] = p[0];
    r2[w + 1] = hp ? p[W] : 0.f;
    __syncthreads();
    float a0 = r0[w], a1 = r0[w + 1], a2 = r0[w + 2];
    float b0 = r1[w],                 b2 = r1[w + 2];
    float c0 = r2[w], c1 = r2[w + 1], c2 = r2[w + 2];
    float gx = (a2 - a0) + 2.f * (b2 - b0) + (c2 - c0);
    float gy = (c0 - a0) + 2.f * (c1 - a1) + (c2 - a2);
    acc = fmaf(gx, gx, acc);
    acc = fmaf(gy, gy, acc);
  }
  float e = acc * (1.f / 64.f);
  edge[bh * W + w] = e;
  // block min/max reduction (wave64 shuffle, then LDS across 4 waves)
  float mn = e, mx = e;
  #pragma unroll
  for (int off = 32; off > 0; off >>= 1) {
    mn = fminf(mn, __shfl_down(mn, off, 64));
    mx = fmaxf(mx, __shfl_down(mx, off, 64));
  }
  const int lane = w & 63, wv = w >> 6;
  if (lane == 0) { smn[wv] = mn; smx[wv] = mx; }
  __syncthreads();
  if (w == 0) {
    mn = fminf(fminf(smn[0], smn[1]), fminf(smn[2], smn[3]));
    mx = fmaxf(fmaxf(smx[0], smx[1]), fmaxf(smx[2], smx[3]));
    // edge >= 0 always -> float order == uint order
    atomicMin(mm + b, __float_as_uint(mn));
    atomicMax(mm + B + b, __float_as_uint(mx));
  }
}

__device__ __forceinline__ void compute_g(float e, float emin, float emax,
                                          float g[7]) {
  float en = (e - emin) / (emax + 1e-6f);        // faithful: denom = emax + eps
  float sigma = SMIN + (SMAX - SMIN) * en;
  float a = 1.0f / (2.0f * sigma * sigma);
  float e1 = __expf(-a);        // exp(-1*a)
  float t2 = e1 * e1;
  float e4 = t2 * t2;           // exp(-4*a)
  float e9 = e4 * e4 * e1;      // exp(-9*a)
  float inv = 1.f / (1.f + 2.f * (e1 + e4 + e9));
  g[0] = e9 * inv; g[1] = e4 * inv; g[2] = e1 * inv; g[3] = inv;
  g[4] = g[2]; g[5] = g[1]; g[6] = g[0];
}

// Thread per output pixel (b,h,w); weights computed once, looped over 64 channels.
__global__ __launch_bounds__(256) void hblur_kernel(
    const float* __restrict__ x, const float* __restrict__ edge,
    const unsigned int* __restrict__ mm, float* __restrict__ dst) {
  const int pix = blockIdx.x * 256 + threadIdx.x;  // b*HW + h*W + w
  const int b = pix >> 16;
  const int w = pix & (W - 1);
  float g[7];
  compute_g(edge[pix], __uint_as_float(mm[b]), __uint_as_float(mm[B + b]), g);
  int off[7];
  #pragma unroll
  for (int i = 0; i < 7; ++i) {
    int wi = w - 3 + i;
    bool ok = (wi >= 0) && (wi < W);
    off[i] = ok ? (i - 3) : 0;   // clamped (valid) address; weight zeroed if OOB
    if (!ok) g[i] = 0.f;
  }
  const size_t base = (size_t)b * CHW + (size_t)(pix & (HW - 1));
  const float* px = x + base;
  float* pd = dst + base;
  for (int c = 0; c < C; ++c) {
    const float* p = px + (size_t)c * HW;
    float acc = g[0] * p[off[0]];
    #pragma unroll
    for (int i = 1; i < 7; ++i) acc = fmaf(g[i], p[off[i]], acc);
    pd[(size_t)c * HW] = acc;
  }
}

// Column-walk vertical blur with rolling 7-row register window.
// HCHUNK == H (one thread per full column) is safe in-place (src == dst):
// each thread reads only rows of its own (b,c,w) column, and the load of a row
// always precedes the store of that same row in program order.
// HCHUNK < H requires src != dst (chunk-boundary rows would race in-place).
template <int HCHUNK>
__global__ __launch_bounds__(256) void vblur_kernel(
    const float* src, float* dst, const float* __restrict__ edge,
    const unsigned int* __restrict__ mm) {
  constexpr int NCH = H / HCHUNK;
  const int t = blockIdx.x * 256 + threadIdx.x;
  const int w = t & (W - 1);
  const int rest = t >> 8;
  const int hc = rest % NCH;
  const int bc = rest / NCH;   // b*C + c
  const int b = bc >> 6;
  const int h0 = hc * HCHUNK;
  const size_t cbase = (size_t)bc * HW + w;
  const float* ps = src + cbase;
  float* pd = dst + cbase;
  const float* pe = edge + (size_t)b * HW + w;
  const float emin = __uint_as_float(mm[b]);
  const float emax = __uint_as_float(mm[B + b]);
  float win[7];
  #pragma unroll
  for (int i = 0; i < 6; ++i) {
    int r = h0 - 3 + i;
    win[i] = (r >= 0 && r < H) ? ps[(size_t)r * W] : 0.f;
  }
  for (int h = h0; h < h0 + HCHUNK; ++h) {
    int r = h + 3;
    win[6] = (r < H) ? ps[(size_t)r * W] : 0.f;
    float g[7];
    compute_g(pe[(size_t)h * W], emin, emax, g);
    float acc = g[0] * win[0];
    #pragma unroll
    for (int i = 1; i < 7; ++i) acc = fmaf(g[i], win[i], acc);
    pd[(size_t)h * W] = acc;
    #pragma unroll
    for (int i = 0; i < 6; ++i) win[i] = win[i + 1];
  }
}

extern "C" void kernel_launch(void* const* d_in, const int* in_sizes, int n_in,
                              void* d_out, int out_size, void* d_ws, size_t ws_size,
                              hipStream_t stream) {
  const float* x = (const float*)d_in[0];
  float* out = (float*)d_out;

  unsigned int* mm = (unsigned int*)d_ws;                 // 2*B uints
  float* edge = (float*)((char*)d_ws + 1024);             // B*H*W floats (1 MB)
  const size_t tmp_off = 1024 + (size_t)B * HW * sizeof(float);
  float* tmp = (float*)((char*)d_ws + tmp_off);           // B*C*H*W floats (64 MB)
  const bool big_ws = ws_size >= tmp_off + (size_t)B * CHW * sizeof(float);

  init_mm_kernel<<<1, 64, 0, stream>>>(mm);
  edge_kernel<<<B * H, 256, 0, stream>>>(x, edge, mm);
  if (big_ws) {
    hblur_kernel<<<(B * HW) / 256, 256, 0, stream>>>(x, edge, mm, tmp);
    vblur_kernel<64><<<(B * C * (H / 64) * W) / 256, 256, 0, stream>>>(tmp, out, edge, mm);
  } else {
    hblur_kernel<<<(B * HW) / 256, 256, 0, stream>>>(x, edge, mm, out);
    vblur_kernel<H><<<(B * C * W) / 256, 256, 0, stream>>>(out, out, edge, mm);
  }
}

// Round 2
// 212.825 us; speedup vs baseline: 1.0650x; 1.0650x over previous
//
#include <hip/hip_runtime.h>
#include <cstddef>

namespace {
constexpr int B = 4, C = 64, H = 256, W = 256;
constexpr int HW = H * W;      // 65536
constexpr int CHW = C * HW;    // 4194304
constexpr float SMIN = 0.6f, SMAX = 1.2f;
}

__global__ void init_mm_kernel(unsigned int* mm) {
  int i = threadIdx.x;
  if (i < B) { mm[i] = 0x7f7fffffu; mm[B + i] = 0u; }
}

__device__ __forceinline__ float4 ld4(const float* p) {
  return *(const float4*)p;
}
__device__ __forceinline__ void st4(float* p, float a, float b, float c, float d) {
  float4 v; v.x = a; v.y = b; v.z = c; v.w = d; *(float4*)p = v;
}

// One block per (b,h) row. lane l owns columns 4l..4l+3 (one wave == one row).
// Wave wv accumulates channels [wv*16, wv*16+16); LDS-combine at the end.
// Horizontal Sobel neighbors via shfl (wave boundary == image boundary -> 0).
__global__ __launch_bounds__(256) void edge_kernel(
    const float* __restrict__ x, float* __restrict__ edge,
    unsigned int* __restrict__ mm) {
  __shared__ float part[3][64][4];
  const int b = blockIdx.x >> 8, h = blockIdx.x & (H - 1);
  const int lane = threadIdx.x & 63, wv = threadIdx.x >> 6;
  const float* base = x + (size_t)b * CHW + (size_t)h * W + 4 * lane;
  const bool hm = (h > 0), hp = (h < H - 1);
  float acc[4] = {0.f, 0.f, 0.f, 0.f};
  for (int c = wv * 16; c < wv * 16 + 16; ++c) {
    const float* p = base + (size_t)c * HW;
    float4 Av = hm ? ld4(p - W) : float4{0.f, 0.f, 0.f, 0.f};
    float4 Bv = ld4(p);
    float4 Cv = hp ? ld4(p + W) : float4{0.f, 0.f, 0.f, 0.f};
    float La = __shfl_up(Av.w, 1), Lb = __shfl_up(Bv.w, 1), Lc = __shfl_up(Cv.w, 1);
    float Ra = __shfl_down(Av.x, 1), Rb = __shfl_down(Bv.x, 1), Rc = __shfl_down(Cv.x, 1);
    if (lane == 0)  { La = 0.f; Lb = 0.f; Lc = 0.f; }
    if (lane == 63) { Ra = 0.f; Rb = 0.f; Rc = 0.f; }
    const float ra[6] = {La, Av.x, Av.y, Av.z, Av.w, Ra};
    const float rb[6] = {Lb, Bv.x, Bv.y, Bv.z, Bv.w, Rb};
    const float rc[6] = {Lc, Cv.x, Cv.y, Cv.z, Cv.w, Rc};
    #pragma unroll
    for (int j = 0; j < 4; ++j) {
      float gx = (ra[j + 2] - ra[j]) + 2.f * (rb[j + 2] - rb[j]) + (rc[j + 2] - rc[j]);
      float gy = (rc[j] - ra[j]) + 2.f * (rc[j + 1] - ra[j + 1]) + (rc[j + 2] - ra[j + 2]);
      acc[j] = fmaf(gx, gx, acc[j]);
      acc[j] = fmaf(gy, gy, acc[j]);
    }
  }
  if (wv > 0) {
    #pragma unroll
    for (int j = 0; j < 4; ++j) part[wv - 1][lane][j] = acc[j];
  }
  __syncthreads();
  if (wv == 0) {
    #pragma unroll
    for (int j = 0; j < 4; ++j)
      acc[j] = (acc[j] + part[0][lane][j] + part[1][lane][j] + part[2][lane][j]) * (1.f / 64.f);
    st4(edge + (size_t)b * HW + (size_t)h * W + 4 * lane, acc[0], acc[1], acc[2], acc[3]);
    float mn = fminf(fminf(acc[0], acc[1]), fminf(acc[2], acc[3]));
    float mx = fmaxf(fmaxf(acc[0], acc[1]), fmaxf(acc[2], acc[3]));
    #pragma unroll
    for (int off = 32; off > 0; off >>= 1) {
      mn = fminf(mn, __shfl_down(mn, off, 64));
      mx = fmaxf(mx, __shfl_down(mx, off, 64));
    }
    if (lane == 0) {
      atomicMin(mm + b, __float_as_uint(mn));       // edge >= 0: float order == uint order
      atomicMax(mm + B + b, __float_as_uint(mx));
    }
  }
}

__device__ __forceinline__ void compute_g(float e, float emin, float inv_den,
                                          float g[7]) {
  float en = (e - emin) * inv_den;
  float sigma = SMIN + (SMAX - SMIN) * en;
  float a = 1.0f / (2.0f * sigma * sigma);
  float e1 = __expf(-a);
  float t2 = e1 * e1;
  float e4 = t2 * t2;
  float e9 = e4 * e4 * e1;
  float inv = 1.f / (1.f + 2.f * (e1 + e4 + e9));
  g[0] = e9 * inv; g[1] = e4 * inv; g[2] = e1 * inv; g[3] = inv;
  g[4] = g[2]; g[5] = g[1]; g[6] = g[0];
}

// Thread per 4-pixel quad (one wave == one row); weights once per pixel,
// channels looped inside; taps from shfl halos (zero at image boundary,
// matching the reference's zero padding with full weights).
__global__ __launch_bounds__(256) void hblur_kernel(
    const float* __restrict__ x, const float* __restrict__ edge,
    const unsigned int* __restrict__ mm, float* __restrict__ dst) {
  const int t = blockIdx.x * 256 + threadIdx.x;
  const int pix4 = t * 4;
  const int b = pix4 >> 16;
  const int lane = threadIdx.x & 63;
  const float emin = __uint_as_float(mm[b]);
  const float inv_den = 1.f / (__uint_as_float(mm[B + b]) + 1e-6f);
  float4 ev = ld4(edge + pix4);
  float g[4][7];
  compute_g(ev.x, emin, inv_den, g[0]);
  compute_g(ev.y, emin, inv_den, g[1]);
  compute_g(ev.z, emin, inv_den, g[2]);
  compute_g(ev.w, emin, inv_den, g[3]);
  const size_t base = (size_t)b * CHW + (size_t)(pix4 & (HW - 1));
  for (int c = 0; c < C; ++c) {
    float4 v = ld4(x + base + (size_t)c * HW);
    float L1 = __shfl_up(v.y, 1), L2 = __shfl_up(v.z, 1), L3 = __shfl_up(v.w, 1);
    float R1 = __shfl_down(v.x, 1), R2 = __shfl_down(v.y, 1), R3 = __shfl_down(v.z, 1);
    if (lane == 0)  { L1 = 0.f; L2 = 0.f; L3 = 0.f; }
    if (lane == 63) { R1 = 0.f; R2 = 0.f; R3 = 0.f; }
    const float win[10] = {L1, L2, L3, v.x, v.y, v.z, v.w, R1, R2, R3};
    float o[4];
    #pragma unroll
    for (int j = 0; j < 4; ++j) {
      float s = g[j][0] * win[j];
      #pragma unroll
      for (int i = 1; i < 7; ++i) s = fmaf(g[j][i], win[j + i], s);
      o[j] = s;
    }
    st4(dst + base + (size_t)c * HW, o[0], o[1], o[2], o[3]);
  }
}

// Thread per 4 columns of one (b,c) plane chunk; rolling 7-row float4 window.
// HCHUNK == H is in-place safe (each thread only touches its own columns,
// row r loaded at h=r-3, stored at h=r). HCHUNK < H needs src != dst.
template <int HCHUNK>
__global__ __launch_bounds__(256) void vblur_kernel(
    const float* src, float* dst, const float* __restrict__ edge,
    const unsigned int* __restrict__ mm) {
  constexpr int NCH = H / HCHUNK;
  const int t = blockIdx.x * 256 + threadIdx.x;
  const int w = (t & 63) * 4;
  const int rest = t >> 6;
  const int hc = rest % NCH;
  const int bc = rest / NCH;   // b*C + c
  const int b = bc >> 6;
  const int h0 = hc * HCHUNK;
  const float* ps = src + (size_t)bc * HW + w;
  float* pd = dst + (size_t)bc * HW + w;
  const float* pe = edge + (size_t)b * HW + w;
  const float emin = __uint_as_float(mm[b]);
  const float inv_den = 1.f / (__uint_as_float(mm[B + b]) + 1e-6f);
  float win[7][4];
  #pragma unroll
  for (int i = 0; i < 6; ++i) {
    int r = h0 - 3 + i;
    if (r >= 0 && r < H) {
      float4 v = ld4(ps + (size_t)r * W);
      win[i][0] = v.x; win[i][1] = v.y; win[i][2] = v.z; win[i][3] = v.w;
    } else {
      win[i][0] = win[i][1] = win[i][2] = win[i][3] = 0.f;
    }
  }
  for (int h = h0; h < h0 + HCHUNK; ++h) {
    int r = h + 3;
    if (r < H) {
      float4 v = ld4(ps + (size_t)r * W);
      win[6][0] = v.x; win[6][1] = v.y; win[6][2] = v.z; win[6][3] = v.w;
    } else {
      win[6][0] = win[6][1] = win[6][2] = win[6][3] = 0.f;
    }
    float4 ev = ld4(pe + (size_t)h * W);
    const float E[4] = {ev.x, ev.y, ev.z, ev.w};
    float o[4];
    #pragma unroll
    for (int j = 0; j < 4; ++j) {
      float g[7];
      compute_g(E[j], emin, inv_den, g);
      float s = g[0] * win[0][j];
      #pragma unroll
      for (int i = 1; i < 7; ++i) s = fmaf(g[i], win[i][j], s);
      o[j] = s;
    }
    st4(pd + (size_t)h * W, o[0], o[1], o[2], o[3]);
    #pragma unroll
    for (int i = 0; i < 6; ++i) {
      #pragma unroll
      for (int j = 0; j < 4; ++j) win[i][j] = win[i + 1][j];
    }
  }
}

extern "C" void kernel_launch(void* const* d_in, const int* in_sizes, int n_in,
                              void* d_out, int out_size, void* d_ws, size_t ws_size,
                              hipStream_t stream) {
  const float* x = (const float*)d_in[0];
  float* out = (float*)d_out;

  unsigned int* mm = (unsigned int*)d_ws;                 // 2*B uints
  float* edge = (float*)((char*)d_ws + 1024);             // B*H*W floats (1 MB)
  const size_t tmp_off = 1024 + (size_t)B * HW * sizeof(float);
  float* tmp = (float*)((char*)d_ws + tmp_off);           // B*C*H*W floats (64 MB)
  const bool big_ws = ws_size >= tmp_off + (size_t)B * CHW * sizeof(float);

  init_mm_kernel<<<1, 64, 0, stream>>>(mm);
  edge_kernel<<<B * H, 256, 0, stream>>>(x, edge, mm);
  if (big_ws) {
    hblur_kernel<<<(B * HW / 4) / 256, 256, 0, stream>>>(x, edge, mm, tmp);
    vblur_kernel<64><<<(B * C * (W / 4) * (H / 64)) / 256, 256, 0, stream>>>(tmp, out, edge, mm);
  } else {
    hblur_kernel<<<(B * HW / 4) / 256, 256, 0, stream>>>(x, edge, mm, out);
    vblur_kernel<H><<<(B * C * (W / 4)) / 256, 256, 0, stream>>>(out, out, edge, mm);
  }
}

// Round 3
// 170.317 us; speedup vs baseline: 1.3308x; 1.2496x over previous
//
#include <hip/hip_runtime.h>
#include <cstddef>

namespace {
constexpr int B = 4, C = 64, H = 256, W = 256;
constexpr int HW = H * W;      // 65536
constexpr int CHW = C * HW;    // 4194304
constexpr int CG = 4;          // channel groups for edge/hblur
constexpr float SMIN = 0.6f, SMAX = 1.2f;
}

__global__ void init_mm_kernel(unsigned int* mm) {
  int i = threadIdx.x;
  if (i < B) { mm[i] = 0x7f7fffffu; mm[B + i] = 0u; }
}

__device__ __forceinline__ float4 ld4(const float* p) {
  return *(const float4*)p;
}
__device__ __forceinline__ void st4(float* p, float a, float b, float c, float d) {
  float4 v; v.x = a; v.y = b; v.z = c; v.w = d; *(float4*)p = v;
}

// Block per (b, h, cg). Wave wv handles 4 channels (fully unrolled -> 12
// independent 16B loads in flight). lane l owns columns 4l..4l+3 (wave == row).
// Horizontal neighbors via shfl (wave boundary == image boundary -> 0).
// Partial sums (16 channels each) written to P[cg][b][h][w].
__global__ __launch_bounds__(256) void edge_kernel(
    const float* __restrict__ x, float* __restrict__ P) {
  __shared__ float part[3][64][4];
  const int cg = blockIdx.x & 3;
  const int bh = blockIdx.x >> 2;
  const int b = bh >> 8, h = bh & (H - 1);
  const int lane = threadIdx.x & 63, wv = threadIdx.x >> 6;
  const float* base = x + (size_t)b * CHW + (size_t)h * W + 4 * lane;
  const bool hm = (h > 0), hp = (h < H - 1);
  float acc[4] = {0.f, 0.f, 0.f, 0.f};
  const int c0 = cg * 16 + wv * 4;
  #pragma unroll
  for (int cc = 0; cc < 4; ++cc) {
    const float* p = base + (size_t)(c0 + cc) * HW;
    float4 Av = hm ? ld4(p - W) : float4{0.f, 0.f, 0.f, 0.f};
    float4 Bv = ld4(p);
    float4 Cv = hp ? ld4(p + W) : float4{0.f, 0.f, 0.f, 0.f};
    float La = __shfl_up(Av.w, 1), Lb = __shfl_up(Bv.w, 1), Lc = __shfl_up(Cv.w, 1);
    float Ra = __shfl_down(Av.x, 1), Rb = __shfl_down(Bv.x, 1), Rc = __shfl_down(Cv.x, 1);
    if (lane == 0)  { La = 0.f; Lb = 0.f; Lc = 0.f; }
    if (lane == 63) { Ra = 0.f; Rb = 0.f; Rc = 0.f; }
    const float ra[6] = {La, Av.x, Av.y, Av.z, Av.w, Ra};
    const float rb[6] = {Lb, Bv.x, Bv.y, Bv.z, Bv.w, Rb};
    const float rc[6] = {Lc, Cv.x, Cv.y, Cv.z, Cv.w, Rc};
    #pragma unroll
    for (int j = 0; j < 4; ++j) {
      float gx = (ra[j + 2] - ra[j]) + 2.f * (rb[j + 2] - rb[j]) + (rc[j + 2] - rc[j]);
      float gy = (rc[j] - ra[j]) + 2.f * (rc[j + 1] - ra[j + 1]) + (rc[j + 2] - ra[j + 2]);
      acc[j] = fmaf(gx, gx, acc[j]);
      acc[j] = fmaf(gy, gy, acc[j]);
    }
  }
  if (wv > 0) {
    #pragma unroll
    for (int j = 0; j < 4; ++j) part[wv - 1][lane][j] = acc[j];
  }
  __syncthreads();
  if (wv == 0) {
    #pragma unroll
    for (int j = 0; j < 4; ++j)
      acc[j] = acc[j] + part[0][lane][j] + part[1][lane][j] + part[2][lane][j];
    st4(P + (size_t)(cg * B + b) * HW + (size_t)h * W + 4 * lane,
        acc[0], acc[1], acc[2], acc[3]);
  }
}

// Sum the 4 partial planes -> edge; per-batch min/max reduce -> mm atomics.
// Block covers 1024 consecutive pixels of one batch plane.
__global__ __launch_bounds__(256) void combine_kernel(
    const float* __restrict__ P, float* __restrict__ edge,
    unsigned int* __restrict__ mm) {
  __shared__ float smn[4], smx[4];
  const int t = blockIdx.x * 256 + threadIdx.x;
  const int pix4 = t * 4;
  const int b = pix4 >> 16;
  const int off = pix4 & (HW - 1);
  float4 s0 = ld4(P + (size_t)(0 * B + b) * HW + off);
  float4 s1 = ld4(P + (size_t)(1 * B + b) * HW + off);
  float4 s2 = ld4(P + (size_t)(2 * B + b) * HW + off);
  float4 s3 = ld4(P + (size_t)(3 * B + b) * HW + off);
  float e0 = (s0.x + s1.x + s2.x + s3.x) * (1.f / 64.f);
  float e1 = (s0.y + s1.y + s2.y + s3.y) * (1.f / 64.f);
  float e2 = (s0.z + s1.z + s2.z + s3.z) * (1.f / 64.f);
  float e3 = (s0.w + s1.w + s2.w + s3.w) * (1.f / 64.f);
  st4(edge + pix4, e0, e1, e2, e3);
  float mn = fminf(fminf(e0, e1), fminf(e2, e3));
  float mx = fmaxf(fmaxf(e0, e1), fmaxf(e2, e3));
  #pragma unroll
  for (int o = 32; o > 0; o >>= 1) {
    mn = fminf(mn, __shfl_down(mn, o, 64));
    mx = fmaxf(mx, __shfl_down(mx, o, 64));
  }
  const int lane = threadIdx.x & 63, wv = threadIdx.x >> 6;
  if (lane == 0) { smn[wv] = mn; smx[wv] = mx; }
  __syncthreads();
  if (threadIdx.x == 0) {
    mn = fminf(fminf(smn[0], smn[1]), fminf(smn[2], smn[3]));
    mx = fmaxf(fmaxf(smx[0], smx[1]), fmaxf(smx[2], smx[3]));
    atomicMin(mm + b, __float_as_uint(mn));       // edge >= 0: float order == uint order
    atomicMax(mm + B + b, __float_as_uint(mx));
  }
}

__device__ __forceinline__ void compute_g(float e, float emin, float inv_den,
                                          float g[7]) {
  float en = (e - emin) * inv_den;
  float sigma = SMIN + (SMAX - SMIN) * en;
  float a = 1.0f / (2.0f * sigma * sigma);
  float e1 = __expf(-a);
  float t2 = e1 * e1;
  float e4 = t2 * t2;
  float e9 = e4 * e4 * e1;
  float inv = 1.f / (1.f + 2.f * (e1 + e4 + e9));
  g[0] = e9 * inv; g[1] = e4 * inv; g[2] = e1 * inv; g[3] = inv;
  g[4] = g[2]; g[5] = g[1]; g[6] = g[0];
}

// Block per (pixel-quad-group, cg): thread owns 4 pixels x 16 channels.
// Weights once per pixel per group; taps via shfl halos.
__global__ __launch_bounds__(256) void hblur_kernel(
    const float* __restrict__ x, const float* __restrict__ edge,
    const unsigned int* __restrict__ mm, float* __restrict__ dst) {
  const int cg = blockIdx.x & 3;
  const int t = (blockIdx.x >> 2) * 256 + threadIdx.x;
  const int pix4 = t * 4;
  const int b = pix4 >> 16;
  const int lane = threadIdx.x & 63;
  const float emin = __uint_as_float(mm[b]);
  const float inv_den = 1.f / (__uint_as_float(mm[B + b]) + 1e-6f);
  float4 ev = ld4(edge + pix4);
  float g[4][7];
  compute_g(ev.x, emin, inv_den, g[0]);
  compute_g(ev.y, emin, inv_den, g[1]);
  compute_g(ev.z, emin, inv_den, g[2]);
  compute_g(ev.w, emin, inv_den, g[3]);
  const size_t base = (size_t)b * CHW + (size_t)(pix4 & (HW - 1));
  #pragma unroll 2
  for (int c = cg * 16; c < cg * 16 + 16; ++c) {
    float4 v = ld4(x + base + (size_t)c * HW);
    float L1 = __shfl_up(v.y, 1), L2 = __shfl_up(v.z, 1), L3 = __shfl_up(v.w, 1);
    float R1 = __shfl_down(v.x, 1), R2 = __shfl_down(v.y, 1), R3 = __shfl_down(v.z, 1);
    if (lane == 0)  { L1 = 0.f; L2 = 0.f; L3 = 0.f; }
    if (lane == 63) { R1 = 0.f; R2 = 0.f; R3 = 0.f; }
    const float win[10] = {L1, L2, L3, v.x, v.y, v.z, v.w, R1, R2, R3};
    float o[4];
    #pragma unroll
    for (int j = 0; j < 4; ++j) {
      float s = g[j][0] * win[j];
      #pragma unroll
      for (int i = 1; i < 7; ++i) s = fmaf(g[j][i], win[j + i], s);
      o[j] = s;
    }
    st4(dst + base + (size_t)c * HW, o[0], o[1], o[2], o[3]);
  }
}

// Thread per 4 columns x HCHUNK rows of one (b,c) plane; rolling 7-row float4
// window. HCHUNK == H is in-place safe; HCHUNK < H needs src != dst.
template <int HCHUNK>
__global__ __launch_bounds__(256) void vblur_kernel(
    const float* src, float* dst, const float* __restrict__ edge,
    const unsigned int* __restrict__ mm) {
  constexpr int NCH = H / HCHUNK;
  const int t = blockIdx.x * 256 + threadIdx.x;
  const int w = (t & 63) * 4;
  const int rest = t >> 6;
  const int hc = rest % NCH;
  const int bc = rest / NCH;   // b*C + c
  const int b = bc >> 6;
  const int h0 = hc * HCHUNK;
  const float* ps = src + (size_t)bc * HW + w;
  float* pd = dst + (size_t)bc * HW + w;
  const float* pe = edge + (size_t)b * HW + w;
  const float emin = __uint_as_float(mm[b]);
  const float inv_den = 1.f / (__uint_as_float(mm[B + b]) + 1e-6f);
  float win[7][4];
  #pragma unroll
  for (int i = 0; i < 6; ++i) {
    int r = h0 - 3 + i;
    if (r >= 0 && r < H) {
      float4 v = ld4(ps + (size_t)r * W);
      win[i][0] = v.x; win[i][1] = v.y; win[i][2] = v.z; win[i][3] = v.w;
    } else {
      win[i][0] = win[i][1] = win[i][2] = win[i][3] = 0.f;
    }
  }
  #pragma unroll 2
  for (int h = h0; h < h0 + HCHUNK; ++h) {
    int r = h + 3;
    if (r < H) {
      float4 v = ld4(ps + (size_t)r * W);
      win[6][0] = v.x; win[6][1] = v.y; win[6][2] = v.z; win[6][3] = v.w;
    } else {
      win[6][0] = win[6][1] = win[6][2] = win[6][3] = 0.f;
    }
    float4 ev = ld4(pe + (size_t)h * W);
    const float E[4] = {ev.x, ev.y, ev.z, ev.w};
    float o[4];
    #pragma unroll
    for (int j = 0; j < 4; ++j) {
      float g[7];
      compute_g(E[j], emin, inv_den, g);
      float s = g[0] * win[0][j];
      #pragma unroll
      for (int i = 1; i < 7; ++i) s = fmaf(g[i], win[i][j], s);
      o[j] = s;
    }
    st4(pd + (size_t)h * W, o[0], o[1], o[2], o[3]);
    #pragma unroll
    for (int i = 0; i < 6; ++i) {
      #pragma unroll
      for (int j = 0; j < 4; ++j) win[i][j] = win[i + 1][j];
    }
  }
}

extern "C" void kernel_launch(void* const* d_in, const int* in_sizes, int n_in,
                              void* d_out, int out_size, void* d_ws, size_t ws_size,
                              hipStream_t stream) {
  const float* x = (const float*)d_in[0];
  float* out = (float*)d_out;

  unsigned int* mm = (unsigned int*)d_ws;                 // 2*B uints
  float* edge = (float*)((char*)d_ws + 1024);             // B*H*W floats (1 MB)
  const size_t tmp_off = 1024 + (size_t)B * HW * sizeof(float);
  float* tmp = (float*)((char*)d_ws + tmp_off);           // B*C*H*W floats (64 MB)
  const bool big_ws = ws_size >= tmp_off + (size_t)B * CHW * sizeof(float);

  // Edge partial planes live in d_out (CG*B*HW floats = 4 MB << out size);
  // overwritten later by the blur passes.
  float* P = out;

  init_mm_kernel<<<1, 64, 0, stream>>>(mm);
  edge_kernel<<<B * H * CG, 256, 0, stream>>>(x, P);
  combine_kernel<<<(B * HW / 4) / 256, 256, 0, stream>>>(P, edge, mm);
  if (big_ws) {
    hblur_kernel<<<CG * (B * HW / 4) / 256, 256, 0, stream>>>(x, edge, mm, tmp);
    vblur_kernel<16><<<(B * C * (W / 4) * (H / 16)) / 256, 256, 0, stream>>>(tmp, out, edge, mm);
  } else {
    hblur_kernel<<<CG * (B * HW / 4) / 256, 256, 0, stream>>>(x, edge, mm, out);
    vblur_kernel<H><<<(B * C * (W / 4)) / 256, 256, 0, stream>>>(out, out, edge, mm);
  }
}

// Round 4
// 151.890 us; speedup vs baseline: 1.4923x; 1.1213x over previous
//
#include <hip/hip_runtime.h>
#include <cstddef>

namespace {
constexpr int B = 4, C = 64, H = 256, W = 256;
constexpr int HW = H * W;      // 65536
constexpr int CHW = C * HW;    // 4194304
constexpr int CG = 4;          // channel groups for edge
constexpr int TH = 32;         // strip height for fused blur
constexpr float SMIN = 0.6f, SMAX = 1.2f;
}

__global__ void init_mm_kernel(unsigned int* mm) {
  int i = threadIdx.x;
  if (i < B) { mm[i] = 0x7f7fffffu; mm[B + i] = 0u; }
}

__device__ __forceinline__ float4 ld4(const float* p) {
  return *(const float4*)p;
}
__device__ __forceinline__ void st4(float* p, float a, float b, float c, float d) {
  float4 v; v.x = a; v.y = b; v.z = c; v.w = d; *(float4*)p = v;
}

// Block per (b, h, cg). Wave wv handles 4 channels (fully unrolled -> 12
// independent 16B loads in flight). lane l owns columns 4l..4l+3 (wave == row).
// Horizontal neighbors via shfl (wave boundary == image boundary -> 0).
// Partial sums (16 channels each) written to P[cg][b][h][w].
__global__ __launch_bounds__(256) void edge_kernel(
    const float* __restrict__ x, float* __restrict__ P) {
  __shared__ float part[3][64][4];
  const int cg = blockIdx.x & 3;
  const int bh = blockIdx.x >> 2;
  const int b = bh >> 8, h = bh & (H - 1);
  const int lane = threadIdx.x & 63, wv = threadIdx.x >> 6;
  const float* base = x + (size_t)b * CHW + (size_t)h * W + 4 * lane;
  const bool hm = (h > 0), hp = (h < H - 1);
  float acc[4] = {0.f, 0.f, 0.f, 0.f};
  const int c0 = cg * 16 + wv * 4;
  #pragma unroll
  for (int cc = 0; cc < 4; ++cc) {
    const float* p = base + (size_t)(c0 + cc) * HW;
    float4 Av = hm ? ld4(p - W) : float4{0.f, 0.f, 0.f, 0.f};
    float4 Bv = ld4(p);
    float4 Cv = hp ? ld4(p + W) : float4{0.f, 0.f, 0.f, 0.f};
    float La = __shfl_up(Av.w, 1), Lb = __shfl_up(Bv.w, 1), Lc = __shfl_up(Cv.w, 1);
    float Ra = __shfl_down(Av.x, 1), Rb = __shfl_down(Bv.x, 1), Rc = __shfl_down(Cv.x, 1);
    if (lane == 0)  { La = 0.f; Lb = 0.f; Lc = 0.f; }
    if (lane == 63) { Ra = 0.f; Rb = 0.f; Rc = 0.f; }
    const float ra[6] = {La, Av.x, Av.y, Av.z, Av.w, Ra};
    const float rb[6] = {Lb, Bv.x, Bv.y, Bv.z, Bv.w, Rb};
    const float rc[6] = {Lc, Cv.x, Cv.y, Cv.z, Cv.w, Rc};
    #pragma unroll
    for (int j = 0; j < 4; ++j) {
      float gx = (ra[j + 2] - ra[j]) + 2.f * (rb[j + 2] - rb[j]) + (rc[j + 2] - rc[j]);
      float gy = (rc[j] - ra[j]) + 2.f * (rc[j + 1] - ra[j + 1]) + (rc[j + 2] - ra[j + 2]);
      acc[j] = fmaf(gx, gx, acc[j]);
      acc[j] = fmaf(gy, gy, acc[j]);
    }
  }
  if (wv > 0) {
    #pragma unroll
    for (int j = 0; j < 4; ++j) part[wv - 1][lane][j] = acc[j];
  }
  __syncthreads();
  if (wv == 0) {
    #pragma unroll
    for (int j = 0; j < 4; ++j)
      acc[j] = acc[j] + part[0][lane][j] + part[1][lane][j] + part[2][lane][j];
    st4(P + (size_t)(cg * B + b) * HW + (size_t)h * W + 4 * lane,
        acc[0], acc[1], acc[2], acc[3]);
  }
}

// Sum the 4 partial planes -> edge; per-batch min/max reduce -> mm atomics.
__global__ __launch_bounds__(256) void combine_kernel(
    const float* __restrict__ P, float* __restrict__ edge,
    unsigned int* __restrict__ mm) {
  __shared__ float smn[4], smx[4];
  const int t = blockIdx.x * 256 + threadIdx.x;
  const int pix4 = t * 4;
  const int b = pix4 >> 16;
  const int off = pix4 & (HW - 1);
  float4 s0 = ld4(P + (size_t)(0 * B + b) * HW + off);
  float4 s1 = ld4(P + (size_t)(1 * B + b) * HW + off);
  float4 s2 = ld4(P + (size_t)(2 * B + b) * HW + off);
  float4 s3 = ld4(P + (size_t)(3 * B + b) * HW + off);
  float e0 = (s0.x + s1.x + s2.x + s3.x) * (1.f / 64.f);
  float e1 = (s0.y + s1.y + s2.y + s3.y) * (1.f / 64.f);
  float e2 = (s0.z + s1.z + s2.z + s3.z) * (1.f / 64.f);
  float e3 = (s0.w + s1.w + s2.w + s3.w) * (1.f / 64.f);
  st4(edge + pix4, e0, e1, e2, e3);
  float mn = fminf(fminf(e0, e1), fminf(e2, e3));
  float mx = fmaxf(fmaxf(e0, e1), fmaxf(e2, e3));
  #pragma unroll
  for (int o = 32; o > 0; o >>= 1) {
    mn = fminf(mn, __shfl_down(mn, o, 64));
    mx = fmaxf(mx, __shfl_down(mx, o, 64));
  }
  const int lane = threadIdx.x & 63, wv = threadIdx.x >> 6;
  if (lane == 0) { smn[wv] = mn; smx[wv] = mx; }
  __syncthreads();
  if (threadIdx.x == 0) {
    mn = fminf(fminf(smn[0], smn[1]), fminf(smn[2], smn[3]));
    mx = fmaxf(fmaxf(smx[0], smx[1]), fmaxf(smx[2], smx[3]));
    atomicMin(mm + b, __float_as_uint(mn));       // edge >= 0: float order == uint order
    atomicMax(mm + B + b, __float_as_uint(mx));
  }
}

// Per-pixel weight table: wt[b][h][w] = {e1, inv} (float2 packed in floats).
// Full 7-tap kernel reconstructs with 7 muls: taps {e9,e4,e1,1,e1,e4,e9}*inv.
__global__ __launch_bounds__(256) void weights_kernel(
    const float* __restrict__ edge, const unsigned int* __restrict__ mm,
    float* __restrict__ wt) {
  const int t = blockIdx.x * 256 + threadIdx.x;
  const int pix4 = t * 4;
  const int b = pix4 >> 16;
  const float emin = __uint_as_float(mm[b]);
  const float inv_den = 1.f / (__uint_as_float(mm[B + b]) + 1e-6f);
  float4 ev = ld4(edge + pix4);
  const float E[4] = {ev.x, ev.y, ev.z, ev.w};
  float r[8];
  #pragma unroll
  for (int j = 0; j < 4; ++j) {
    float en = (E[j] - emin) * inv_den;
    float sg = SMIN + (SMAX - SMIN) * en;
    float a = 1.0f / (2.0f * sg * sg);
    float e1 = __expf(-a);
    float t2 = e1 * e1, e4 = t2 * t2, e9 = e4 * e4 * e1;
    float inv = 1.f / (1.f + 2.f * (e1 + e4 + e9));
    r[2 * j] = e1; r[2 * j + 1] = inv;
  }
  st4(wt + (size_t)pix4 * 2,     r[0], r[1], r[2], r[3]);
  st4(wt + (size_t)pix4 * 2 + 4, r[4], r[5], r[6], r[7]);
}

__device__ __forceinline__ void recon_g(float e1, float inv, float g[7]) {
  float t2 = e1 * e1, e4 = t2 * t2, e9 = e4 * e4 * e1;
  g[3] = inv; g[2] = e1 * inv; g[1] = e4 * inv; g[0] = e9 * inv;
  g[4] = g[2]; g[5] = g[1]; g[6] = g[0];
}

// Fused h+v blur. Block per (b, c, 32-row strip): stage TH+6 rows, hblur in
// registers (shfl halos) -> LDS, one barrier, vblur from LDS with a rolling
// 7-row register window, store to out. Weights from the wt table (L2-resident).
__global__ __launch_bounds__(256) void fusedblur_kernel(
    const float* __restrict__ x, const float* __restrict__ wt,
    float* __restrict__ out) {
  __shared__ float hb[TH + 6][W];
  const int s = blockIdx.x & (H / TH - 1);       // H/TH == 8
  const int bc = blockIdx.x >> 3;                // b*C + c
  const int b = bc >> 6;
  const int h0 = s * TH;
  const int lane = threadIdx.x & 63, wv = threadIdx.x >> 6;
  const float* xp = x + (size_t)bc * HW + 4 * lane;
  const float* wp = wt + (size_t)b * HW * 2 + 8 * lane;
  float* op = out + (size_t)bc * HW + 4 * lane;

  // Stage 1: hblur rows h0-3 .. h0+TH+2 into LDS (zero rows outside image).
  for (int r = wv; r < TH + 6; r += 4) {
    const int gh = h0 - 3 + r;
    float4 o = {0.f, 0.f, 0.f, 0.f};
    if (gh >= 0 && gh < H) {
      float4 v = ld4(xp + (size_t)gh * W);
      float4 q0 = ld4(wp + (size_t)gh * W * 2);
      float4 q1 = ld4(wp + (size_t)gh * W * 2 + 4);
      float L1 = __shfl_up(v.y, 1), L2 = __shfl_up(v.z, 1), L3 = __shfl_up(v.w, 1);
      float R1 = __shfl_down(v.x, 1), R2 = __shfl_down(v.y, 1), R3 = __shfl_down(v.z, 1);
      if (lane == 0)  { L1 = 0.f; L2 = 0.f; L3 = 0.f; }
      if (lane == 63) { R1 = 0.f; R2 = 0.f; R3 = 0.f; }
      const float win[10] = {L1, L2, L3, v.x, v.y, v.z, v.w, R1, R2, R3};
      const float E1[4] = {q0.x, q0.z, q1.x, q1.z};
      const float IV[4] = {q0.y, q0.w, q1.y, q1.w};
      float acc[4];
      #pragma unroll
      for (int j = 0; j < 4; ++j) {
        float g[7]; recon_g(E1[j], IV[j], g);
        float sacc = g[0] * win[j];
        #pragma unroll
        for (int i = 1; i < 7; ++i) sacc = fmaf(g[i], win[j + i], sacc);
        acc[j] = sacc;
      }
      o.x = acc[0]; o.y = acc[1]; o.z = acc[2]; o.w = acc[3];
    }
    *(float4*)&hb[r][4 * lane] = o;
  }
  __syncthreads();

  // Stage 2: vblur. Wave wv owns output rows [wv*8, wv*8+8), rolling window.
  const int r0 = wv * 8;
  float win7[7][4];
  #pragma unroll
  for (int i = 0; i < 7; ++i) {
    float4 v = *(const float4*)&hb[r0 + i][4 * lane];
    win7[i][0] = v.x; win7[i][1] = v.y; win7[i][2] = v.z; win7[i][3] = v.w;
  }
  #pragma unroll
  for (int k = 0; k < 8; ++k) {
    const int gh = h0 + r0 + k;
    float4 q0 = ld4(wp + (size_t)gh * W * 2);
    float4 q1 = ld4(wp + (size_t)gh * W * 2 + 4);
    const float E1[4] = {q0.x, q0.z, q1.x, q1.z};
    const float IV[4] = {q0.y, q0.w, q1.y, q1.w};
    float acc[4];
    #pragma unroll
    for (int j = 0; j < 4; ++j) {
      float g[7]; recon_g(E1[j], IV[j], g);
      float sacc = g[0] * win7[0][j];
      #pragma unroll
      for (int i = 1; i < 7; ++i) sacc = fmaf(g[i], win7[i][j], sacc);
      acc[j] = sacc;
    }
    st4(op + (size_t)gh * W, acc[0], acc[1], acc[2], acc[3]);
    if (k < 7) {
      #pragma unroll
      for (int i = 0; i < 6; ++i) {
        #pragma unroll
        for (int j = 0; j < 4; ++j) win7[i][j] = win7[i + 1][j];
      }
      float4 nv = *(const float4*)&hb[r0 + k + 7][4 * lane];
      win7[6][0] = nv.x; win7[6][1] = nv.y; win7[6][2] = nv.z; win7[6][3] = nv.w;
    }
  }
}

extern "C" void kernel_launch(void* const* d_in, const int* in_sizes, int n_in,
                              void* d_out, int out_size, void* d_ws, size_t ws_size,
                              hipStream_t stream) {
  const float* x = (const float*)d_in[0];
  float* out = (float*)d_out;

  unsigned int* mm = (unsigned int*)d_ws;                       // 2*B uints
  float* edge = (float*)((char*)d_ws + 1024);                   // B*HW floats (1 MB)
  float* wt = (float*)((char*)d_ws + 1024 + (size_t)B * HW * 4); // B*HW*2 floats (2 MB)

  // Edge partial planes live in d_out (CG*B*HW floats = 4 MB); overwritten
  // later by the fused blur, which writes every output element.
  float* P = out;

  init_mm_kernel<<<1, 64, 0, stream>>>(mm);
  edge_kernel<<<B * H * CG, 256, 0, stream>>>(x, P);
  combine_kernel<<<(B * HW / 4) / 256, 256, 0, stream>>>(P, edge, mm);
  weights_kernel<<<(B * HW / 4) / 256, 256, 0, stream>>>(edge, mm, wt);
  fusedblur_kernel<<<B * C * (H / TH), 256, 0, stream>>>(x, wt, out);
}

// Round 5
// 148.832 us; speedup vs baseline: 1.5230x; 1.0205x over previous
//
#include <hip/hip_runtime.h>
#include <cstddef>

namespace {
constexpr int B = 4, C = 64, H = 256, W = 256;
constexpr int HW = H * W;      // 65536
constexpr int CHW = C * HW;    // 4194304
constexpr int CG = 4;          // channel groups for edge
constexpr int TH = 64;         // strip height for fused blur
constexpr float SMIN = 0.6f, SMAX = 1.2f;
}

__device__ __forceinline__ float4 ld4(const float* p) {
  return *(const float4*)p;
}
__device__ __forceinline__ void st4(float* p, float a, float b, float c, float d) {
  float4 v; v.x = a; v.y = b; v.z = c; v.w = d; *(float4*)p = v;
}

// Block per (b, h, cg), XCD-band swizzled: xcd = blockIdx%8 owns rows
// [xcd*32, xcd*32+32); within a band, h iterates fastest per (cg,b) so
// adjacent rows stream through the same XCD's L2 (halo rows become L2 hits).
// Wave wv handles 4 channels fully unrolled (12 independent 16B loads).
// lane l owns columns 4l..4l+3 (wave == row); horizontal neighbors via shfl.
// Partial sums (16 channels) -> P[cg][b][h][w]. Block 0 also inits mm.
__global__ __launch_bounds__(256) void edge_kernel(
    const float* __restrict__ x, float* __restrict__ P,
    unsigned int* __restrict__ mm) {
  __shared__ float part[3][64][4];
  if (blockIdx.x == 0 && threadIdx.x < 2 * B)
    mm[threadIdx.x] = (threadIdx.x < B) ? 0x7f7fffffu : 0u;
  const int xcd = blockIdx.x & 7;
  const int slot = blockIdx.x >> 3;          // 0..511
  const int hh = slot & 31;
  const int cb = slot >> 5;                  // 0..15 = cg*B + b
  const int h = xcd * 32 + hh;
  const int cg = cb >> 2;
  const int b = cb & 3;
  const int lane = threadIdx.x & 63, wv = threadIdx.x >> 6;
  const float* base = x + (size_t)b * CHW + (size_t)h * W + 4 * lane;
  const bool hm = (h > 0), hp = (h < H - 1);
  float acc[4] = {0.f, 0.f, 0.f, 0.f};
  const int c0 = cg * 16 + wv * 4;
  #pragma unroll
  for (int cc = 0; cc < 4; ++cc) {
    const float* p = base + (size_t)(c0 + cc) * HW;
    float4 Av = hm ? ld4(p - W) : float4{0.f, 0.f, 0.f, 0.f};
    float4 Bv = ld4(p);
    float4 Cv = hp ? ld4(p + W) : float4{0.f, 0.f, 0.f, 0.f};
    float La = __shfl_up(Av.w, 1), Lb = __shfl_up(Bv.w, 1), Lc = __shfl_up(Cv.w, 1);
    float Ra = __shfl_down(Av.x, 1), Rb = __shfl_down(Bv.x, 1), Rc = __shfl_down(Cv.x, 1);
    if (lane == 0)  { La = 0.f; Lb = 0.f; Lc = 0.f; }
    if (lane == 63) { Ra = 0.f; Rb = 0.f; Rc = 0.f; }
    const float ra[6] = {La, Av.x, Av.y, Av.z, Av.w, Ra};
    const float rb[6] = {Lb, Bv.x, Bv.y, Bv.z, Bv.w, Rb};
    const float rc[6] = {Lc, Cv.x, Cv.y, Cv.z, Cv.w, Rc};
    #pragma unroll
    for (int j = 0; j < 4; ++j) {
      float gx = (ra[j + 2] - ra[j]) + 2.f * (rb[j + 2] - rb[j]) + (rc[j + 2] - rc[j]);
      float gy = (rc[j] - ra[j]) + 2.f * (rc[j + 1] - ra[j + 1]) + (rc[j + 2] - ra[j + 2]);
      acc[j] = fmaf(gx, gx, acc[j]);
      acc[j] = fmaf(gy, gy, acc[j]);
    }
  }
  if (wv > 0) {
    #pragma unroll
    for (int j = 0; j < 4; ++j) part[wv - 1][lane][j] = acc[j];
  }
  __syncthreads();
  if (wv == 0) {
    #pragma unroll
    for (int j = 0; j < 4; ++j)
      acc[j] = acc[j] + part[0][lane][j] + part[1][lane][j] + part[2][lane][j];
    st4(P + (size_t)(cg * B + b) * HW + (size_t)h * W + 4 * lane,
        acc[0], acc[1], acc[2], acc[3]);
  }
}

// Sum the 4 partial planes -> edge; per-batch min/max reduce -> mm atomics.
__global__ __launch_bounds__(256) void combine_kernel(
    const float* __restrict__ P, float* __restrict__ edge,
    unsigned int* __restrict__ mm) {
  __shared__ float smn[4], smx[4];
  const int t = blockIdx.x * 256 + threadIdx.x;
  const int pix4 = t * 4;
  const int b = pix4 >> 16;
  const int off = pix4 & (HW - 1);
  float4 s0 = ld4(P + (size_t)(0 * B + b) * HW + off);
  float4 s1 = ld4(P + (size_t)(1 * B + b) * HW + off);
  float4 s2 = ld4(P + (size_t)(2 * B + b) * HW + off);
  float4 s3 = ld4(P + (size_t)(3 * B + b) * HW + off);
  float e0 = (s0.x + s1.x + s2.x + s3.x) * (1.f / 64.f);
  float e1 = (s0.y + s1.y + s2.y + s3.y) * (1.f / 64.f);
  float e2 = (s0.z + s1.z + s2.z + s3.z) * (1.f / 64.f);
  float e3 = (s0.w + s1.w + s2.w + s3.w) * (1.f / 64.f);
  st4(edge + pix4, e0, e1, e2, e3);
  float mn = fminf(fminf(e0, e1), fminf(e2, e3));
  float mx = fmaxf(fmaxf(e0, e1), fmaxf(e2, e3));
  #pragma unroll
  for (int o = 32; o > 0; o >>= 1) {
    mn = fminf(mn, __shfl_down(mn, o, 64));
    mx = fmaxf(mx, __shfl_down(mx, o, 64));
  }
  const int lane = threadIdx.x & 63, wv = threadIdx.x >> 6;
  if (lane == 0) { smn[wv] = mn; smx[wv] = mx; }
  __syncthreads();
  if (threadIdx.x == 0) {
    mn = fminf(fminf(smn[0], smn[1]), fminf(smn[2], smn[3]));
    mx = fmaxf(fmaxf(smx[0], smx[1]), fmaxf(smx[2], smx[3]));
    atomicMin(mm + b, __float_as_uint(mn));       // edge >= 0: float order == uint order
    atomicMax(mm + B + b, __float_as_uint(mx));
  }
}

// Per-pixel weight table: wt[b][h][w] = {e1, inv}. Full 7-tap kernel is
// reconstructed with 4 muls: taps {e9,e4,e1,1,e1,e4,e9}*inv.
__global__ __launch_bounds__(256) void weights_kernel(
    const float* __restrict__ edge, const unsigned int* __restrict__ mm,
    float* __restrict__ wt) {
  const int t = blockIdx.x * 256 + threadIdx.x;
  const int pix4 = t * 4;
  const int b = pix4 >> 16;
  const float emin = __uint_as_float(mm[b]);
  const float inv_den = 1.f / (__uint_as_float(mm[B + b]) + 1e-6f);
  float4 ev = ld4(edge + pix4);
  const float E[4] = {ev.x, ev.y, ev.z, ev.w};
  float r[8];
  #pragma unroll
  for (int j = 0; j < 4; ++j) {
    float en = (E[j] - emin) * inv_den;
    float sg = SMIN + (SMAX - SMIN) * en;
    float a = 1.0f / (2.0f * sg * sg);
    float e1 = __expf(-a);
    float t2 = e1 * e1, e4 = t2 * t2, e9 = e4 * e4 * e1;
    float inv = 1.f / (1.f + 2.f * (e1 + e4 + e9));
    r[2 * j] = e1; r[2 * j + 1] = inv;
  }
  st4(wt + (size_t)pix4 * 2,     r[0], r[1], r[2], r[3]);
  st4(wt + (size_t)pix4 * 2 + 4, r[4], r[5], r[6], r[7]);
}

__device__ __forceinline__ void recon_g(float e1, float inv, float g[7]) {
  float t2 = e1 * e1, e4 = t2 * t2, e9 = e4 * e4 * e1;
  g[3] = inv; g[2] = e1 * inv; g[1] = e4 * inv; g[0] = e9 * inv;
  g[4] = g[2]; g[5] = g[1]; g[6] = g[0];
}

// Fused h+v blur. Block per (b, c, 64-row strip): stage TH+6 hblurred rows in
// LDS (70 KB -> 2 blocks/CU), one barrier, vblur with rolling 7-row register
// window, store to out. XCD swizzle: each XCD owns 32 (b,c) planes with strips
// iterating fastest, so the 6 halo rows of adjacent strips hit the local L2.
__global__ __launch_bounds__(256) void fusedblur_kernel(
    const float* __restrict__ x, const float* __restrict__ wt,
    float* __restrict__ out) {
  __shared__ float hb[TH + 6][W];
  const int xcd = blockIdx.x & 7;
  const int slot = blockIdx.x >> 3;              // 0..127
  const int s = slot & 3;                        // strip (H/TH == 4)
  const int bc = xcd * 32 + (slot >> 2);         // b*C + c
  const int b = bc >> 6;
  const int h0 = s * TH;
  const int lane = threadIdx.x & 63, wv = threadIdx.x >> 6;
  const float* xp = x + (size_t)bc * HW + 4 * lane;
  const float* wp = wt + (size_t)b * HW * 2 + 8 * lane;
  float* op = out + (size_t)bc * HW + 4 * lane;

  // Stage 1: hblur rows h0-3 .. h0+TH+2 into LDS (zero rows outside image).
  for (int r = wv; r < TH + 6; r += 4) {
    const int gh = h0 - 3 + r;
    float4 o = {0.f, 0.f, 0.f, 0.f};
    if (gh >= 0 && gh < H) {
      float4 v = ld4(xp + (size_t)gh * W);
      float4 q0 = ld4(wp + (size_t)gh * W * 2);
      float4 q1 = ld4(wp + (size_t)gh * W * 2 + 4);
      float L1 = __shfl_up(v.y, 1), L2 = __shfl_up(v.z, 1), L3 = __shfl_up(v.w, 1);
      float R1 = __shfl_down(v.x, 1), R2 = __shfl_down(v.y, 1), R3 = __shfl_down(v.z, 1);
      if (lane == 0)  { L1 = 0.f; L2 = 0.f; L3 = 0.f; }
      if (lane == 63) { R1 = 0.f; R2 = 0.f; R3 = 0.f; }
      const float win[10] = {L1, L2, L3, v.x, v.y, v.z, v.w, R1, R2, R3};
      const float E1[4] = {q0.x, q0.z, q1.x, q1.z};
      const float IV[4] = {q0.y, q0.w, q1.y, q1.w};
      float acc[4];
      #pragma unroll
      for (int j = 0; j < 4; ++j) {
        float g[7]; recon_g(E1[j], IV[j], g);
        float sacc = g[0] * win[j];
        #pragma unroll
        for (int i = 1; i < 7; ++i) sacc = fmaf(g[i], win[j + i], sacc);
        acc[j] = sacc;
      }
      o.x = acc[0]; o.y = acc[1]; o.z = acc[2]; o.w = acc[3];
    }
    *(float4*)&hb[r][4 * lane] = o;
  }
  __syncthreads();

  // Stage 2: vblur. Wave wv owns output rows [wv*16, wv*16+16), rolling window.
  const int r0 = wv * 16;
  float win7[7][4];
  #pragma unroll
  for (int i = 0; i < 7; ++i) {
    float4 v = *(const float4*)&hb[r0 + i][4 * lane];
    win7[i][0] = v.x; win7[i][1] = v.y; win7[i][2] = v.z; win7[i][3] = v.w;
  }
  #pragma unroll
  for (int k = 0; k < 16; ++k) {
    const int gh = h0 + r0 + k;
    float4 q0 = ld4(wp + (size_t)gh * W * 2);
    float4 q1 = ld4(wp + (size_t)gh * W * 2 + 4);
    const float E1[4] = {q0.x, q0.z, q1.x, q1.z};
    const float IV[4] = {q0.y, q0.w, q1.y, q1.w};
    float acc[4];
    #pragma unroll
    for (int j = 0; j < 4; ++j) {
      float g[7]; recon_g(E1[j], IV[j], g);
      float sacc = g[0] * win7[0][j];
      #pragma unroll
      for (int i = 1; i < 7; ++i) sacc = fmaf(g[i], win7[i][j], sacc);
      acc[j] = sacc;
    }
    st4(op + (size_t)gh * W, acc[0], acc[1], acc[2], acc[3]);
    if (k < 15) {
      #pragma unroll
      for (int i = 0; i < 6; ++i) {
        #pragma unroll
        for (int j = 0; j < 4; ++j) win7[i][j] = win7[i + 1][j];
      }
      float4 nv = *(const float4*)&hb[r0 + k + 7][4 * lane];
      win7[6][0] = nv.x; win7[6][1] = nv.y; win7[6][2] = nv.z; win7[6][3] = nv.w;
    }
  }
}

extern "C" void kernel_launch(void* const* d_in, const int* in_sizes, int n_in,
                              void* d_out, int out_size, void* d_ws, size_t ws_size,
                              hipStream_t stream) {
  const float* x = (const float*)d_in[0];
  float* out = (float*)d_out;

  unsigned int* mm = (unsigned int*)d_ws;                        // 2*B uints
  float* edge = (float*)((char*)d_ws + 1024);                    // B*HW floats (1 MB)
  float* wt = (float*)((char*)d_ws + 1024 + (size_t)B * HW * 4); // B*HW*2 floats (2 MB)

  // Edge partial planes live in d_out (CG*B*HW floats = 4 MB); overwritten
  // later by the fused blur, which writes every output element.
  float* P = out;

  edge_kernel<<<B * H * CG, 256, 0, stream>>>(x, P, mm);
  combine_kernel<<<(B * HW / 4) / 256, 256, 0, stream>>>(P, edge, mm);
  weights_kernel<<<(B * HW / 4) / 256, 256, 0, stream>>>(edge, mm, wt);
  fusedblur_kernel<<<B * C * (H / TH), 256, 0, stream>>>(x, wt, out);
}

// Round 6
// 145.884 us; speedup vs baseline: 1.5537x; 1.0202x over previous
//
#include <hip/hip_runtime.h>
#include <cstddef>

namespace {
constexpr int B = 4, C = 64, H = 256, W = 256;
constexpr int HW = H * W;      // 65536
constexpr int CHW = C * HW;    // 4194304
constexpr int CG = 4;          // channel groups for edge
constexpr int TH = 64;         // strip height for fused blur
constexpr float SMIN = 0.6f, SMAX = 1.2f;
}

__device__ __forceinline__ float4 ld4(const float* p) {
  return *(const float4*)p;
}
__device__ __forceinline__ void st4(float* p, float a, float b, float c, float d) {
  float4 v; v.x = a; v.y = b; v.z = c; v.w = d; *(float4*)p = v;
}

// Block per (b, cg, 4-row band), XCD-band swizzled: xcd = blockIdx%8 owns rows
// [xcd*32, xcd*32+32), bands iterate fastest within (cg,b) so halo rows of
// adjacent bands stream through the same XCD's L2. Each wave handles 4
// channels fully unrolled; per channel it loads 6 rows (rolling halo) and
// emits 4 rows of Sobel-energy partials -> 1.5x logical reads instead of 3x.
// lane l owns columns 4l..4l+3 (wave == row); horizontal neighbors via shfl.
// Partial sums (16 channels) -> P[cg][b][h][w]. Block 0 also inits mm.
__global__ __launch_bounds__(256) void edge_kernel(
    const float* __restrict__ x, float* __restrict__ P,
    unsigned int* __restrict__ mm) {
  __shared__ float part[4][4][64][4];   // [wave][row][lane][px]
  if (blockIdx.x == 0 && threadIdx.x < 2 * B)
    mm[threadIdx.x] = (threadIdx.x < B) ? 0x7f7fffffu : 0u;
  const int xcd = blockIdx.x & 7;
  const int slot = blockIdx.x >> 3;          // 0..127
  const int hbb = slot & 7;                  // band within the XCD's 32 rows
  const int cb = slot >> 3;                  // 0..15 = cg*B + b
  const int h0 = xcd * 32 + hbb * 4;
  const int cg = cb >> 2;
  const int b = cb & 3;
  const int lane = threadIdx.x & 63, wv = threadIdx.x >> 6;
  const float* base = x + (size_t)b * CHW + 4 * lane;
  const int c0 = cg * 16 + wv * 4;
  float acc[4][4] = {};
  #pragma unroll
  for (int cc = 0; cc < 4; ++cc) {
    const float* p = base + (size_t)(c0 + cc) * HW;
    float4 R[6];
    #pragma unroll
    for (int i = 0; i < 6; ++i) {
      const int gh = h0 - 1 + i;
      R[i] = (gh >= 0 && gh < H) ? ld4(p + (size_t)gh * W)
                                 : float4{0.f, 0.f, 0.f, 0.f};
    }
    float Lh[6], Rh[6];
    #pragma unroll
    for (int i = 0; i < 6; ++i) {
      Lh[i] = __shfl_up(R[i].w, 1);
      Rh[i] = __shfl_down(R[i].x, 1);
    }
    if (lane == 0) {
      #pragma unroll
      for (int i = 0; i < 6; ++i) Lh[i] = 0.f;
    }
    if (lane == 63) {
      #pragma unroll
      for (int i = 0; i < 6; ++i) Rh[i] = 0.f;
    }
    #pragma unroll
    for (int r = 0; r < 4; ++r) {
      const float ra[6] = {Lh[r],     R[r].x,     R[r].y,     R[r].z,     R[r].w,     Rh[r]};
      const float rb[6] = {Lh[r + 1], R[r + 1].x, R[r + 1].y, R[r + 1].z, R[r + 1].w, Rh[r + 1]};
      const float rc[6] = {Lh[r + 2], R[r + 2].x, R[r + 2].y, R[r + 2].z, R[r + 2].w, Rh[r + 2]};
      #pragma unroll
      for (int j = 0; j < 4; ++j) {
        float gx = (ra[j + 2] - ra[j]) + 2.f * (rb[j + 2] - rb[j]) + (rc[j + 2] - rc[j]);
        float gy = (rc[j] - ra[j]) + 2.f * (rc[j + 1] - ra[j + 1]) + (rc[j + 2] - ra[j + 2]);
        acc[r][j] = fmaf(gx, gx, acc[r][j]);
        acc[r][j] = fmaf(gy, gy, acc[r][j]);
      }
    }
  }
  #pragma unroll
  for (int r = 0; r < 4; ++r)
    #pragma unroll
    for (int j = 0; j < 4; ++j) part[wv][r][lane][j] = acc[r][j];
  __syncthreads();
  {
    const int r = wv;                       // wave wv combines + writes row wv
    float s[4];
    #pragma unroll
    for (int j = 0; j < 4; ++j)
      s[j] = part[0][r][lane][j] + part[1][r][lane][j] +
             part[2][r][lane][j] + part[3][r][lane][j];
    st4(P + (size_t)(cg * B + b) * HW + (size_t)(h0 + r) * W + 4 * lane,
        s[0], s[1], s[2], s[3]);
  }
}

// Sum the 4 partial planes -> edge; per-batch min/max reduce -> mm atomics.
__global__ __launch_bounds__(256) void combine_kernel(
    const float* __restrict__ P, float* __restrict__ edge,
    unsigned int* __restrict__ mm) {
  __shared__ float smn[4], smx[4];
  const int t = blockIdx.x * 256 + threadIdx.x;
  const int pix4 = t * 4;
  const int b = pix4 >> 16;
  const int off = pix4 & (HW - 1);
  float4 s0 = ld4(P + (size_t)(0 * B + b) * HW + off);
  float4 s1 = ld4(P + (size_t)(1 * B + b) * HW + off);
  float4 s2 = ld4(P + (size_t)(2 * B + b) * HW + off);
  float4 s3 = ld4(P + (size_t)(3 * B + b) * HW + off);
  float e0 = (s0.x + s1.x + s2.x + s3.x) * (1.f / 64.f);
  float e1 = (s0.y + s1.y + s2.y + s3.y) * (1.f / 64.f);
  float e2 = (s0.z + s1.z + s2.z + s3.z) * (1.f / 64.f);
  float e3 = (s0.w + s1.w + s2.w + s3.w) * (1.f / 64.f);
  st4(edge + pix4, e0, e1, e2, e3);
  float mn = fminf(fminf(e0, e1), fminf(e2, e3));
  float mx = fmaxf(fmaxf(e0, e1), fmaxf(e2, e3));
  #pragma unroll
  for (int o = 32; o > 0; o >>= 1) {
    mn = fminf(mn, __shfl_down(mn, o, 64));
    mx = fmaxf(mx, __shfl_down(mx, o, 64));
  }
  const int lane = threadIdx.x & 63, wv = threadIdx.x >> 6;
  if (lane == 0) { smn[wv] = mn; smx[wv] = mx; }
  __syncthreads();
  if (threadIdx.x == 0) {
    mn = fminf(fminf(smn[0], smn[1]), fminf(smn[2], smn[3]));
    mx = fmaxf(fmaxf(smx[0], smx[1]), fmaxf(smx[2], smx[3]));
    atomicMin(mm + b, __float_as_uint(mn));       // edge >= 0: float order == uint order
    atomicMax(mm + B + b, __float_as_uint(mx));
  }
}

// Per-pixel weight table: wt[b][h][w] = {e1, inv}. Full 7-tap kernel is
// reconstructed with 4 muls: taps {e9,e4,e1,1,e1,e4,e9}*inv.
__global__ __launch_bounds__(256) void weights_kernel(
    const float* __restrict__ edge, const unsigned int* __restrict__ mm,
    float* __restrict__ wt) {
  const int t = blockIdx.x * 256 + threadIdx.x;
  const int pix4 = t * 4;
  const int b = pix4 >> 16;
  const float emin = __uint_as_float(mm[b]);
  const float inv_den = 1.f / (__uint_as_float(mm[B + b]) + 1e-6f);
  float4 ev = ld4(edge + pix4);
  const float E[4] = {ev.x, ev.y, ev.z, ev.w};
  float r[8];
  #pragma unroll
  for (int j = 0; j < 4; ++j) {
    float en = (E[j] - emin) * inv_den;
    float sg = SMIN + (SMAX - SMIN) * en;
    float a = 1.0f / (2.0f * sg * sg);
    float e1 = __expf(-a);
    float t2 = e1 * e1, e4 = t2 * t2, e9 = e4 * e4 * e1;
    float inv = 1.f / (1.f + 2.f * (e1 + e4 + e9));
    r[2 * j] = e1; r[2 * j + 1] = inv;
  }
  st4(wt + (size_t)pix4 * 2,     r[0], r[1], r[2], r[3]);
  st4(wt + (size_t)pix4 * 2 + 4, r[4], r[5], r[6], r[7]);
}

__device__ __forceinline__ void recon_g(float e1, float inv, float g[7]) {
  float t2 = e1 * e1, e4 = t2 * t2, e9 = e4 * e4 * e1;
  g[3] = inv; g[2] = e1 * inv; g[1] = e4 * inv; g[0] = e9 * inv;
  g[4] = g[2]; g[5] = g[1]; g[6] = g[0];
}

// Fused h+v blur. Block per (b, c, 64-row strip): stage TH+6 hblurred rows in
// LDS (70 KB -> 2 blocks/CU), one barrier, vblur with rolling 7-row register
// window, store to out. XCD swizzle: each XCD owns 32 (b,c) planes with strips
// iterating fastest, so the 6 halo rows of adjacent strips hit the local L2.
__global__ __launch_bounds__(256) void fusedblur_kernel(
    const float* __restrict__ x, const float* __restrict__ wt,
    float* __restrict__ out) {
  __shared__ float hb[TH + 6][W];
  const int xcd = blockIdx.x & 7;
  const int slot = blockIdx.x >> 3;              // 0..127
  const int s = slot & 3;                        // strip (H/TH == 4)
  const int bc = xcd * 32 + (slot >> 2);         // b*C + c
  const int b = bc >> 6;
  const int h0 = s * TH;
  const int lane = threadIdx.x & 63, wv = threadIdx.x >> 6;
  const float* xp = x + (size_t)bc * HW + 4 * lane;
  const float* wp = wt + (size_t)b * HW * 2 + 8 * lane;
  float* op = out + (size_t)bc * HW + 4 * lane;

  // Stage 1: hblur rows h0-3 .. h0+TH+2 into LDS (zero rows outside image).
  for (int r = wv; r < TH + 6; r += 4) {
    const int gh = h0 - 3 + r;
    float4 o = {0.f, 0.f, 0.f, 0.f};
    if (gh >= 0 && gh < H) {
      float4 v = ld4(xp + (size_t)gh * W);
      float4 q0 = ld4(wp + (size_t)gh * W * 2);
      float4 q1 = ld4(wp + (size_t)gh * W * 2 + 4);
      float L1 = __shfl_up(v.y, 1), L2 = __shfl_up(v.z, 1), L3 = __shfl_up(v.w, 1);
      float R1 = __shfl_down(v.x, 1), R2 = __shfl_down(v.y, 1), R3 = __shfl_down(v.z, 1);
      if (lane == 0)  { L1 = 0.f; L2 = 0.f; L3 = 0.f; }
      if (lane == 63) { R1 = 0.f; R2 = 0.f; R3 = 0.f; }
      const float win[10] = {L1, L2, L3, v.x, v.y, v.z, v.w, R1, R2, R3};
      const float E1[4] = {q0.x, q0.z, q1.x, q1.z};
      const float IV[4] = {q0.y, q0.w, q1.y, q1.w};
      float acc[4];
      #pragma unroll
      for (int j = 0; j < 4; ++j) {
        float g[7]; recon_g(E1[j], IV[j], g);
        float sacc = g[0] * win[j];
        #pragma unroll
        for (int i = 1; i < 7; ++i) sacc = fmaf(g[i], win[j + i], sacc);
        acc[j] = sacc;
      }
      o.x = acc[0]; o.y = acc[1]; o.z = acc[2]; o.w = acc[3];
    }
    *(float4*)&hb[r][4 * lane] = o;
  }
  __syncthreads();

  // Stage 2: vblur. Wave wv owns output rows [wv*16, wv*16+16), rolling window.
  const int r0 = wv * 16;
  float win7[7][4];
  #pragma unroll
  for (int i = 0; i < 7; ++i) {
    float4 v = *(const float4*)&hb[r0 + i][4 * lane];
    win7[i][0] = v.x; win7[i][1] = v.y; win7[i][2] = v.z; win7[i][3] = v.w;
  }
  #pragma unroll
  for (int k = 0; k < 16; ++k) {
    const int gh = h0 + r0 + k;
    float4 q0 = ld4(wp + (size_t)gh * W * 2);
    float4 q1 = ld4(wp + (size_t)gh * W * 2 + 4);
    const float E1[4] = {q0.x, q0.z, q1.x, q1.z};
    const float IV[4] = {q0.y, q0.w, q1.y, q1.w};
    float acc[4];
    #pragma unroll
    for (int j = 0; j < 4; ++j) {
      float g[7]; recon_g(E1[j], IV[j], g);
      float sacc = g[0] * win7[0][j];
      #pragma unroll
      for (int i = 1; i < 7; ++i) sacc = fmaf(g[i], win7[i][j], sacc);
      acc[j] = sacc;
    }
    st4(op + (size_t)gh * W, acc[0], acc[1], acc[2], acc[3]);
    if (k < 15) {
      #pragma unroll
      for (int i = 0; i < 6; ++i) {
        #pragma unroll
        for (int j = 0; j < 4; ++j) win7[i][j] = win7[i + 1][j];
      }
      float4 nv = *(const float4*)&hb[r0 + k + 7][4 * lane];
      win7[6][0] = nv.x; win7[6][1] = nv.y; win7[6][2] = nv.z; win7[6][3] = nv.w;
    }
  }
}

extern "C" void kernel_launch(void* const* d_in, const int* in_sizes, int n_in,
                              void* d_out, int out_size, void* d_ws, size_t ws_size,
                              hipStream_t stream) {
  const float* x = (const float*)d_in[0];
  float* out = (float*)d_out;

  unsigned int* mm = (unsigned int*)d_ws;                        // 2*B uints
  float* edge = (float*)((char*)d_ws + 1024);                    // B*HW floats (1 MB)
  float* wt = (float*)((char*)d_ws + 1024 + (size_t)B * HW * 4); // B*HW*2 floats (2 MB)

  // Edge partial planes live in d_out (CG*B*HW floats = 4 MB); overwritten
  // later by the fused blur, which writes every output element.
  float* P = out;

  edge_kernel<<<B * CG * (H / 4), 256, 0, stream>>>(x, P, mm);
  combine_kernel<<<(B * HW / 4) / 256, 256, 0, stream>>>(P, edge, mm);
  weights_kernel<<<(B * HW / 4) / 256, 256, 0, stream>>>(edge, mm, wt);
  fusedblur_kernel<<<B * C * (H / TH), 256, 0, stream>>>(x, wt, out);
}

// Round 7
// 143.093 us; speedup vs baseline: 1.5840x; 1.0195x over previous
//
#include <hip/hip_runtime.h>
#include <cstddef>

namespace {
constexpr int B = 4, C = 64, H = 256, W = 256;
constexpr int HW = H * W;      // 65536
constexpr int CHW = C * HW;    // 4194304
constexpr int CG = 4;          // channel groups for edge
constexpr int TH = 32;         // strip height for fused blur (38.5 KB LDS -> 4 blocks/CU)
constexpr float SMIN = 0.6f, SMAX = 1.2f;
}

__device__ __forceinline__ float4 ld4(const float* p) {
  return *(const float4*)p;
}
__device__ __forceinline__ void st4(float* p, float a, float b, float c, float d) {
  float4 v; v.x = a; v.y = b; v.z = c; v.w = d; *(float4*)p = v;
}

// Block per (b, cg, 4-row band), XCD-band swizzled: xcd = blockIdx%8 owns rows
// [xcd*32, xcd*32+32), bands iterate fastest within (cg,b) so halo rows of
// adjacent bands stream through the same XCD's L2. Each wave handles 4
// channels fully unrolled; per channel it loads 6 rows (rolling halo) and
// emits 4 rows of Sobel-energy partials -> 1.5x logical reads instead of 3x.
// lane l owns columns 4l..4l+3 (wave == row); horizontal neighbors via shfl.
// Partial sums (16 channels) -> P[cg][b][h][w]. Block 0 also inits mm.
__global__ __launch_bounds__(256) void edge_kernel(
    const float* __restrict__ x, float* __restrict__ P,
    unsigned int* __restrict__ mm) {
  __shared__ float part[4][4][64][4];   // [wave][row][lane][px]
  if (blockIdx.x == 0 && threadIdx.x < 2 * B)
    mm[threadIdx.x] = (threadIdx.x < B) ? 0x7f7fffffu : 0u;
  const int xcd = blockIdx.x & 7;
  const int slot = blockIdx.x >> 3;          // 0..127
  const int hbb = slot & 7;                  // band within the XCD's 32 rows
  const int cb = slot >> 3;                  // 0..15 = cg*B + b
  const int h0 = xcd * 32 + hbb * 4;
  const int cg = cb >> 2;
  const int b = cb & 3;
  const int lane = threadIdx.x & 63, wv = threadIdx.x >> 6;
  const float* base = x + (size_t)b * CHW + 4 * lane;
  const int c0 = cg * 16 + wv * 4;
  float acc[4][4] = {};
  #pragma unroll
  for (int cc = 0; cc < 4; ++cc) {
    const float* p = base + (size_t)(c0 + cc) * HW;
    float4 R[6];
    #pragma unroll
    for (int i = 0; i < 6; ++i) {
      const int gh = h0 - 1 + i;
      R[i] = (gh >= 0 && gh < H) ? ld4(p + (size_t)gh * W)
                                 : float4{0.f, 0.f, 0.f, 0.f};
    }
    float Lh[6], Rh[6];
    #pragma unroll
    for (int i = 0; i < 6; ++i) {
      Lh[i] = __shfl_up(R[i].w, 1);
      Rh[i] = __shfl_down(R[i].x, 1);
    }
    if (lane == 0) {
      #pragma unroll
      for (int i = 0; i < 6; ++i) Lh[i] = 0.f;
    }
    if (lane == 63) {
      #pragma unroll
      for (int i = 0; i < 6; ++i) Rh[i] = 0.f;
    }
    #pragma unroll
    for (int r = 0; r < 4; ++r) {
      const float ra[6] = {Lh[r],     R[r].x,     R[r].y,     R[r].z,     R[r].w,     Rh[r]};
      const float rb[6] = {Lh[r + 1], R[r + 1].x, R[r + 1].y, R[r + 1].z, R[r + 1].w, Rh[r + 1]};
      const float rc[6] = {Lh[r + 2], R[r + 2].x, R[r + 2].y, R[r + 2].z, R[r + 2].w, Rh[r + 2]};
      #pragma unroll
      for (int j = 0; j < 4; ++j) {
        float gx = (ra[j + 2] - ra[j]) + 2.f * (rb[j + 2] - rb[j]) + (rc[j + 2] - rc[j]);
        float gy = (rc[j] - ra[j]) + 2.f * (rc[j + 1] - ra[j + 1]) + (rc[j + 2] - ra[j + 2]);
        acc[r][j] = fmaf(gx, gx, acc[r][j]);
        acc[r][j] = fmaf(gy, gy, acc[r][j]);
      }
    }
  }
  #pragma unroll
  for (int r = 0; r < 4; ++r)
    #pragma unroll
    for (int j = 0; j < 4; ++j) part[wv][r][lane][j] = acc[r][j];
  __syncthreads();
  {
    const int r = wv;                       // wave wv combines + writes row wv
    float s[4];
    #pragma unroll
    for (int j = 0; j < 4; ++j)
      s[j] = part[0][r][lane][j] + part[1][r][lane][j] +
             part[2][r][lane][j] + part[3][r][lane][j];
    st4(P + (size_t)(cg * B + b) * HW + (size_t)(h0 + r) * W + 4 * lane,
        s[0], s[1], s[2], s[3]);
  }
}

// Sum the 4 partial planes -> edge; per-batch min/max reduce -> mm atomics.
__global__ __launch_bounds__(256) void combine_kernel(
    const float* __restrict__ P, float* __restrict__ edge,
    unsigned int* __restrict__ mm) {
  __shared__ float smn[4], smx[4];
  const int t = blockIdx.x * 256 + threadIdx.x;
  const int pix4 = t * 4;
  const int b = pix4 >> 16;
  const int off = pix4 & (HW - 1);
  float4 s0 = ld4(P + (size_t)(0 * B + b) * HW + off);
  float4 s1 = ld4(P + (size_t)(1 * B + b) * HW + off);
  float4 s2 = ld4(P + (size_t)(2 * B + b) * HW + off);
  float4 s3 = ld4(P + (size_t)(3 * B + b) * HW + off);
  float e0 = (s0.x + s1.x + s2.x + s3.x) * (1.f / 64.f);
  float e1 = (s0.y + s1.y + s2.y + s3.y) * (1.f / 64.f);
  float e2 = (s0.z + s1.z + s2.z + s3.z) * (1.f / 64.f);
  float e3 = (s0.w + s1.w + s2.w + s3.w) * (1.f / 64.f);
  st4(edge + pix4, e0, e1, e2, e3);
  float mn = fminf(fminf(e0, e1), fminf(e2, e3));
  float mx = fmaxf(fmaxf(e0, e1), fmaxf(e2, e3));
  #pragma unroll
  for (int o = 32; o > 0; o >>= 1) {
    mn = fminf(mn, __shfl_down(mn, o, 64));
    mx = fmaxf(mx, __shfl_down(mx, o, 64));
  }
  const int lane = threadIdx.x & 63, wv = threadIdx.x >> 6;
  if (lane == 0) { smn[wv] = mn; smx[wv] = mx; }
  __syncthreads();
  if (threadIdx.x == 0) {
    mn = fminf(fminf(smn[0], smn[1]), fminf(smn[2], smn[3]));
    mx = fmaxf(fmaxf(smx[0], smx[1]), fmaxf(smx[2], smx[3]));
    atomicMin(mm + b, __float_as_uint(mn));       // edge >= 0: float order == uint order
    atomicMax(mm + B + b, __float_as_uint(mx));
  }
}

// Per-pixel weight table: wt[b][h][w] = {e1, inv}. Full 7-tap kernel is
// reconstructed with 4 muls: taps {e9,e4,e1,1,e1,e4,e9}*inv.
__global__ __launch_bounds__(256) void weights_kernel(
    const float* __restrict__ edge, const unsigned int* __restrict__ mm,
    float* __restrict__ wt) {
  const int t = blockIdx.x * 256 + threadIdx.x;
  const int pix4 = t * 4;
  const int b = pix4 >> 16;
  const float emin = __uint_as_float(mm[b]);
  const float inv_den = 1.f / (__uint_as_float(mm[B + b]) + 1e-6f);
  float4 ev = ld4(edge + pix4);
  const float E[4] = {ev.x, ev.y, ev.z, ev.w};
  float r[8];
  #pragma unroll
  for (int j = 0; j < 4; ++j) {
    float en = (E[j] - emin) * inv_den;
    float sg = SMIN + (SMAX - SMIN) * en;
    float a = 1.0f / (2.0f * sg * sg);
    float e1 = __expf(-a);
    float t2 = e1 * e1, e4 = t2 * t2, e9 = e4 * e4 * e1;
    float inv = 1.f / (1.f + 2.f * (e1 + e4 + e9));
    r[2 * j] = e1; r[2 * j + 1] = inv;
  }
  st4(wt + (size_t)pix4 * 2,     r[0], r[1], r[2], r[3]);
  st4(wt + (size_t)pix4 * 2 + 4, r[4], r[5], r[6], r[7]);
}

__device__ __forceinline__ void recon_g(float e1, float inv, float g[7]) {
  float t2 = e1 * e1, e4 = t2 * t2, e9 = e4 * e4 * e1;
  g[3] = inv; g[2] = e1 * inv; g[1] = e4 * inv; g[0] = e9 * inv;
  g[4] = g[2]; g[5] = g[1]; g[6] = g[0];
}

// Fused h+v blur. Block per (b, c, 32-row strip): stage TH+6 hblurred rows in
// LDS (38.5 KB -> 4 blocks/CU), one barrier, vblur with rolling 7-row register
// window, store to out. XCD swizzle: each XCD owns 32 (b,c) planes with strips
// iterating fastest, so the 6 halo rows of adjacent strips hit the local L2.
// TH=64 tried (R6): 70 KB LDS halved occupancy -> latency-bound regression.
__global__ __launch_bounds__(256) void fusedblur_kernel(
    const float* __restrict__ x, const float* __restrict__ wt,
    float* __restrict__ out) {
  __shared__ float hb[TH + 6][W];
  const int xcd = blockIdx.x & 7;
  const int slot = blockIdx.x >> 3;              // 0..255
  const int s = slot & 7;                        // strip (H/TH == 8)
  const int bc = xcd * 32 + (slot >> 3);         // b*C + c
  const int b = bc >> 6;
  const int h0 = s * TH;
  const int lane = threadIdx.x & 63, wv = threadIdx.x >> 6;
  const float* xp = x + (size_t)bc * HW + 4 * lane;
  const float* wp = wt + (size_t)b * HW * 2 + 8 * lane;
  float* op = out + (size_t)bc * HW + 4 * lane;

  // Stage 1: hblur rows h0-3 .. h0+TH+2 into LDS (zero rows outside image).
  for (int r = wv; r < TH + 6; r += 4) {
    const int gh = h0 - 3 + r;
    float4 o = {0.f, 0.f, 0.f, 0.f};
    if (gh >= 0 && gh < H) {
      float4 v = ld4(xp + (size_t)gh * W);
      float4 q0 = ld4(wp + (size_t)gh * W * 2);
      float4 q1 = ld4(wp + (size_t)gh * W * 2 + 4);
      float L1 = __shfl_up(v.y, 1), L2 = __shfl_up(v.z, 1), L3 = __shfl_up(v.w, 1);
      float R1 = __shfl_down(v.x, 1), R2 = __shfl_down(v.y, 1), R3 = __shfl_down(v.z, 1);
      if (lane == 0)  { L1 = 0.f; L2 = 0.f; L3 = 0.f; }
      if (lane == 63) { R1 = 0.f; R2 = 0.f; R3 = 0.f; }
      const float win[10] = {L1, L2, L3, v.x, v.y, v.z, v.w, R1, R2, R3};
      const float E1[4] = {q0.x, q0.z, q1.x, q1.z};
      const float IV[4] = {q0.y, q0.w, q1.y, q1.w};
      float acc[4];
      #pragma unroll
      for (int j = 0; j < 4; ++j) {
        float g[7]; recon_g(E1[j], IV[j], g);
        float sacc = g[0] * win[j];
        #pragma unroll
        for (int i = 1; i < 7; ++i) sacc = fmaf(g[i], win[j + i], sacc);
        acc[j] = sacc;
      }
      o.x = acc[0]; o.y = acc[1]; o.z = acc[2]; o.w = acc[3];
    }
    *(float4*)&hb[r][4 * lane] = o;
  }
  __syncthreads();

  // Stage 2: vblur. Wave wv owns output rows [wv*8, wv*8+8), rolling window.
  const int r0 = wv * 8;
  float win7[7][4];
  #pragma unroll
  for (int i = 0; i < 7; ++i) {
    float4 v = *(const float4*)&hb[r0 + i][4 * lane];
    win7[i][0] = v.x; win7[i][1] = v.y; win7[i][2] = v.z; win7[i][3] = v.w;
  }
  #pragma unroll
  for (int k = 0; k < 8; ++k) {
    const int gh = h0 + r0 + k;
    float4 q0 = ld4(wp + (size_t)gh * W * 2);
    float4 q1 = ld4(wp + (size_t)gh * W * 2 + 4);
    const float E1[4] = {q0.x, q0.z, q1.x, q1.z};
    const float IV[4] = {q0.y, q0.w, q1.y, q1.w};
    float acc[4];
    #pragma unroll
    for (int j = 0; j < 4; ++j) {
      float g[7]; recon_g(E1[j], IV[j], g);
      float sacc = g[0] * win7[0][j];
      #pragma unroll
      for (int i = 1; i < 7; ++i) sacc = fmaf(g[i], win7[i][j], sacc);
      acc[j] = sacc;
    }
    st4(op + (size_t)gh * W, acc[0], acc[1], acc[2], acc[3]);
    if (k < 7) {
      #pragma unroll
      for (int i = 0; i < 6; ++i) {
        #pragma unroll
        for (int j = 0; j < 4; ++j) win7[i][j] = win7[i + 1][j];
      }
      float4 nv = *(const float4*)&hb[r0 + k + 7][4 * lane];
      win7[6][0] = nv.x; win7[6][1] = nv.y; win7[6][2] = nv.z; win7[6][3] = nv.w;
    }
  }
}

extern "C" void kernel_launch(void* const* d_in, const int* in_sizes, int n_in,
                              void* d_out, int out_size, void* d_ws, size_t ws_size,
                              hipStream_t stream) {
  const float* x = (const float*)d_in[0];
  float* out = (float*)d_out;

  unsigned int* mm = (unsigned int*)d_ws;                        // 2*B uints
  float* edge = (float*)((char*)d_ws + 1024);                    // B*HW floats (1 MB)
  float* wt = (float*)((char*)d_ws + 1024 + (size_t)B * HW * 4); // B*HW*2 floats (2 MB)

  // Edge partial planes live in d_out (CG*B*HW floats = 4 MB); overwritten
  // later by the fused blur, which writes every output element.
  float* P = out;

  edge_kernel<<<B * CG * (H / 4), 256, 0, stream>>>(x, P, mm);
  combine_kernel<<<(B * HW / 4) / 256, 256, 0, stream>>>(P, edge, mm);
  weights_kernel<<<(B * HW / 4) / 256, 256, 0, stream>>>(edge, mm, wt);
  fusedblur_kernel<<<B * C * (H / TH), 256, 0, stream>>>(x, wt, out);
}